// Round 7
// baseline (2920.891 us; speedup 1.0000x reference)
//
#include <hip/hip_runtime.h>
#include <hip/hip_bf16.h>

typedef __attribute__((ext_vector_type(8))) short bf16x8;
typedef __attribute__((ext_vector_type(4))) float f32x4;

#define NB 64
#define HD 1024
#define LD 256
#define OD 512
#define SQ 256
#define NGATE 128
#define NOUT 32
#define HN (NB * HD)
#define FSTR 32  // flag stride in u32 (128 B): one LLC line per flag, single writer

static __device__ __forceinline__ unsigned short f2bf(float f) {
  union { float f; unsigned u; } v; v.f = f;
  unsigned r = v.u + 0x7fffu + ((v.u >> 16) & 1u);
  return (unsigned short)(r >> 16);
}

static __device__ __forceinline__ bf16x8 cvt8(f32x4 x, f32x4 y) {
  bf16x8 r;
  r[0] = (short)f2bf(x[0]); r[1] = (short)f2bf(x[1]);
  r[2] = (short)f2bf(x[2]); r[3] = (short)f2bf(x[3]);
  r[4] = (short)f2bf(y[0]); r[5] = (short)f2bf(y[1]);
  r[6] = (short)f2bf(y[2]); r[7] = (short)f2bf(y[3]);
  return r;
}

static __device__ __forceinline__ bf16x8 ld_cvt(const float* p) {
  const f32x4* q = (const f32x4*)p;
  return cvt8(q[0], q[1]);
}
static __device__ __forceinline__ bf16x8 ld_cvt_sum(const float* p, const float* p2) {
  const f32x4* q = (const f32x4*)p;
  const f32x4* r = (const f32x4*)p2;
  return cvt8(q[0] + r[0], q[1] + r[1]);
}

static __device__ __forceinline__ float sigm(float x) { return 1.0f / (1.0f + __expf(-x)); }
static __device__ __forceinline__ float tanh_f(float x) {
  float t = __expf(-2.0f * fabsf(x));
  float r = (1.0f - t) / (1.0f + t);
  return copysignf(r, x);
}

static __device__ __forceinline__ unsigned ldflag(const unsigned* p) {
  return __hip_atomic_load(p, __ATOMIC_RELAXED, __HIP_MEMORY_SCOPE_AGENT);
}
static __device__ __forceinline__ void stflag(unsigned* p, unsigned v) {
  __hip_atomic_store(p, v, __ATOMIC_RELAXED, __HIP_MEMORY_SCOPE_AGENT);
}

// agent-coherent (LLC-direct, sc1) h reads
static __device__ __forceinline__ bf16x8 ld_h16(const unsigned short* p) {
  const unsigned long long* q = (const unsigned long long*)p;
  unsigned long long lo = __hip_atomic_load(q, __ATOMIC_RELAXED, __HIP_MEMORY_SCOPE_AGENT);
  unsigned long long hi = __hip_atomic_load(q + 1, __ATOMIC_RELAXED, __HIP_MEMORY_SCOPE_AGENT);
  union { unsigned long long v[2]; bf16x8 b; } u;
  u.v[0] = lo; u.v[1] = hi;
  return u.b;
}

// ---------------- h0 = latent @ fc_w^T + fc_b ---------------------------------
__global__ void fc_h0(const float* __restrict__ latent, const float* __restrict__ fcw,
                      const float* __restrict__ fcb, unsigned short* __restrict__ h0) {
  int gid = blockIdx.x * 256 + threadIdx.x;   // 65536 = 64*1024
  int b = gid >> 10, j = gid & 1023;
  const f32x4* lr = (const f32x4*)(latent + (size_t)b * LD);
  const f32x4* wr = (const f32x4*)(fcw + (size_t)j * LD);
  float s = fcb[j];
#pragma unroll 8
  for (int k = 0; k < LD / 4; ++k) {
    f32x4 a = lr[k], w = wr[k];
    s += a[0] * w[0] + a[1] * w[1] + a[2] * w[2] + a[3] * w[3];
  }
  h0[(size_t)b * HD + j] = f2bf(s);
}

// ---------------- zero flag region ---------------------------------------------
__global__ void zero_k(unsigned* __restrict__ flags) {
  for (int i = threadIdx.x; i < (NGATE + NOUT) * FSTR; i += 256) flags[i] = 0;
}

// ---------------- persistent LSTM kernel --------------------------------------
// blocks 0..127: gate WGs (8 hidden units each). blocks 128..159: out WGs (16 out rows).
// flags[i*FSTR]        (i<128): gate WG i completed steps count
// flags[(128+j)*FSTR]  (j<32) : out WG j has finished READING h_o (value o)
__global__ __launch_bounds__(256, 1)
void lstm_persist(const float* __restrict__ w_ih, const float* __restrict__ w_hh,
                  const float* __restrict__ b_ih, const float* __restrict__ b_hh,
                  const float* __restrict__ out_w, const float* __restrict__ out_b,
                  unsigned* __restrict__ flags, unsigned short* __restrict__ hbuf,
                  float* __restrict__ dout) {
  __shared__ float smem[4352];
  const int tid = threadIdx.x;
  const int lane = tid & 63;
  const int wid = tid >> 6;
  const int col = lane & 15;   // MFMA n/row-within-tile index
  const int kg = lane >> 4;    // MFMA k-group

  if (blockIdx.x < NGATE) {
    // =================== GATE WG ===================
    const int wg = blockIdx.x;
    const int mh = wid & 1;   // batch half (32)
    const int kh = wid >> 1;  // k half (512)
    const int u = col & 7;
    const int grow0 = ((col >> 3) + 0) * HD + wg * 8 + u;  // rows: i|f
    const int grow1 = ((col >> 3) + 2) * HD + wg * 8 + u;  // rows: g|o
    const int kb = kh * 512 + kg * 8;

    const float bias0 = b_ih[grow0] + b_hh[grow0];
    const float bias1 = b_ih[grow1] + b_hh[grow1];

    // persistent combined weights in registers (for t>=1); 128 VGPR/lane.
    // __launch_bounds__(256,1) gives the 512-VGPR budget so these stay resident.
    bf16x8 Wf0[16], Wf1[16];
#pragma unroll
    for (int ks = 0; ks < 16; ++ks) {
      Wf0[ks] = ld_cvt_sum(w_ih + (size_t)grow0 * HD + kb + ks * 32,
                           w_hh + (size_t)grow0 * HD + kb + ks * 32);
      Wf1[ks] = ld_cvt_sum(w_ih + (size_t)grow1 * HD + kb + ks * 32,
                           w_hh + (size_t)grow1 * HD + kb + ks * 32);
    }

    float c[2][4];
#pragma unroll
    for (int mt = 0; mt < 2; ++mt)
#pragma unroll
      for (int r = 0; r < 4; ++r) c[mt][r] = 0.0f;

    // wave0 poll pointers: lane covers gate flags {lane, lane+64}, out flag lane&31
    const unsigned* gp0 = flags + (size_t)lane * FSTR;
    const unsigned* gp1 = flags + (size_t)(lane + 64) * FSTR;
    const unsigned* op = flags + (size_t)(NGATE + (lane & 31)) * FSTR;

    for (int g = 0; g < SQ; ++g) {
      if (wid == 0 && g >= 1) {
        unsigned gtgt = (unsigned)g;                       // all gates done step g-1
        unsigned otgt = (g >= 4) ? (unsigned)(g - 3) : 0u; // out WGs done reading h_{g-3}
        for (;;) {
          unsigned m = min(ldflag(gp0), ldflag(gp1));
          unsigned om = (lane < 32) ? ldflag(op) : 0xffffffffu;
          if (__all((int)(m >= gtgt && om >= otgt))) break;
          __builtin_amdgcn_s_sleep(1);
        }
      }
      __syncthreads();
      asm volatile("" ::: "memory");

      const unsigned short* hb = hbuf + (size_t)(g & 3) * HN;
      const unsigned short* a0b = hb + (size_t)(mh * 32 + col) * HD + kb;
      const unsigned short* a1b = hb + (size_t)(mh * 32 + 16 + col) * HD + kb;

      // Preload ALL A-fragments first (source order => atomics issue back-to-back,
      // one LLC RTT total instead of one per ks iteration).
      bf16x8 A0[16], A1[16];
#pragma unroll
      for (int ks = 0; ks < 16; ++ks) {
        A0[ks] = ld_h16(a0b + ks * 32);
        A1[ks] = ld_h16(a1b + ks * 32);
      }

      f32x4 acc[2][2];
#pragma unroll
      for (int mt = 0; mt < 2; ++mt)
#pragma unroll
        for (int nt = 0; nt < 2; ++nt) acc[mt][nt] = (f32x4){0.f, 0.f, 0.f, 0.f};

      if (g == 0) {  // x0 = 0: gates = h0 @ w_hh^T (stream B-frags from global)
#pragma unroll
        for (int ks = 0; ks < 16; ++ks) {
          bf16x8 w0 = ld_cvt(w_hh + (size_t)grow0 * HD + kb + ks * 32);
          bf16x8 w1 = ld_cvt(w_hh + (size_t)grow1 * HD + kb + ks * 32);
          acc[0][0] = __builtin_amdgcn_mfma_f32_16x16x32_bf16(A0[ks], w0, acc[0][0], 0, 0, 0);
          acc[0][1] = __builtin_amdgcn_mfma_f32_16x16x32_bf16(A0[ks], w1, acc[0][1], 0, 0, 0);
          acc[1][0] = __builtin_amdgcn_mfma_f32_16x16x32_bf16(A1[ks], w0, acc[1][0], 0, 0, 0);
          acc[1][1] = __builtin_amdgcn_mfma_f32_16x16x32_bf16(A1[ks], w1, acc[1][1], 0, 0, 0);
        }
      } else {
#pragma unroll
        for (int ks = 0; ks < 16; ++ks) {
          acc[0][0] = __builtin_amdgcn_mfma_f32_16x16x32_bf16(A0[ks], Wf0[ks], acc[0][0], 0, 0, 0);
          acc[0][1] = __builtin_amdgcn_mfma_f32_16x16x32_bf16(A0[ks], Wf1[ks], acc[0][1], 0, 0, 0);
          acc[1][0] = __builtin_amdgcn_mfma_f32_16x16x32_bf16(A1[ks], Wf0[ks], acc[1][0], 0, 0, 0);
          acc[1][1] = __builtin_amdgcn_mfma_f32_16x16x32_bf16(A1[ks], Wf1[ks], acc[1][1], 0, 0, 0);
        }
      }

      // K-reduction across kh via LDS
      if (kh == 1) {
#pragma unroll
        for (int mt = 0; mt < 2; ++mt)
#pragma unroll
          for (int nt = 0; nt < 2; ++nt)
#pragma unroll
            for (int r = 0; r < 4; ++r)
              smem[(((mh * 2 + mt) * 2 + nt) * 16 + kg * 4 + r) * 17 + col] = acc[mt][nt][r];
      }
      __syncthreads();
      if (kh == 0) {
        unsigned short* hn = hbuf + (size_t)((g + 1) & 3) * HN;
#pragma unroll
        for (int mt = 0; mt < 2; ++mt) {
#pragma unroll
          for (int r = 0; r < 4; ++r) {
            float gi = acc[mt][0][r] +
                       smem[(((mh * 2 + mt) * 2 + 0) * 16 + kg * 4 + r) * 17 + col] + bias0;
            float gg = acc[mt][1][r] +
                       smem[(((mh * 2 + mt) * 2 + 1) * 16 + kg * 4 + r) * 17 + col] + bias1;
            float gi_p = __shfl_xor(gi, 8);
            float gg_p = __shfl_xor(gg, 8);
            float I = (col < 8) ? gi : gi_p;
            float F = (col < 8) ? gi_p : gi;
            float G = (col < 8) ? gg : gg_p;
            float Oo = (col < 8) ? gg_p : gg;
            float cn = sigm(F) * c[mt][r] + sigm(I) * tanh_f(G);
            c[mt][r] = cn;
            float hv = sigm(Oo) * tanh_f(cn);
            // publish h via packed u32 atomic swap: commits AT the LLC (no posted-
            // store window vs the flag).
            unsigned hb16 = (unsigned)f2bf(hv);
            unsigned pv = (unsigned)__shfl_xor((int)hb16, 1);
            if (col < 8 && (col & 1) == 0) {
              unsigned val = (hb16 & 0xffffu) | (pv << 16);
              unsigned* p = (unsigned*)(hn +
                  (size_t)(mh * 32 + mt * 16 + kg * 4 + r) * HD + wg * 8 + col);
              __hip_atomic_exchange(p, val, __ATOMIC_RELAXED, __HIP_MEMORY_SCOPE_AGENT);
            }
          }
        }
      }
      __syncthreads();  // each wave drains vmcnt (swaps committed at LLC) before flag
      if (tid == 0) stflag(flags + (size_t)wg * FSTR, (unsigned)(g + 1));
    }
  } else {
    // =================== OUT WG ===================
    const int wgo = blockIdx.x - NGATE;
    const int kq = wid;  // k quarter (256)
    const int orow = wgo * 16 + col;
    bf16x8 Bo[8];
#pragma unroll
    for (int ks = 0; ks < 8; ++ks)
      Bo[ks] = ld_cvt(out_w + (size_t)orow * HD + kq * 256 + ks * 32 + kg * 8);
    const float ob = out_b[wgo * 16 + (tid & 15)];

    const unsigned* gp0 = flags + (size_t)lane * FSTR;
    const unsigned* gp1 = flags + (size_t)(lane + 64) * FSTR;

    for (int o = 1; o <= SQ; ++o) {
      if (wid == 0) {
        unsigned tg = (unsigned)o;  // h_o ready
        for (;;) {
          unsigned m = min(ldflag(gp0), ldflag(gp1));
          if (__all((int)(m >= tg))) break;
          __builtin_amdgcn_s_sleep(1);
        }
      }
      __syncthreads();
      asm volatile("" ::: "memory");

      const unsigned short* hb = hbuf + (size_t)(o & 3) * HN;

      // Preload all 32 A-fragments (source order) for one pipelined LLC burst.
      bf16x8 A[8][4];
#pragma unroll
      for (int ks = 0; ks < 8; ++ks)
#pragma unroll
        for (int mt = 0; mt < 4; ++mt)
          A[ks][mt] = ld_h16(hb + (size_t)(mt * 16 + col) * HD + kq * 256 + ks * 32 + kg * 8);

      f32x4 oacc[4];
#pragma unroll
      for (int mt = 0; mt < 4; ++mt) oacc[mt] = (f32x4){0.f, 0.f, 0.f, 0.f};
#pragma unroll
      for (int ks = 0; ks < 8; ++ks)
#pragma unroll
        for (int mt = 0; mt < 4; ++mt)
          oacc[mt] = __builtin_amdgcn_mfma_f32_16x16x32_bf16(A[ks][mt], Bo[ks], oacc[mt], 0, 0, 0);

      // partials to LDS
#pragma unroll
      for (int mt = 0; mt < 4; ++mt)
#pragma unroll
        for (int r = 0; r < 4; ++r)
          smem[((kq * 4 + mt) * 16 + kg * 4 + r) * 17 + col] = oacc[mt][r];
      __syncthreads();  // drains h loads (vmcnt) + orders LDS
      if (tid == 0) stflag(flags + (size_t)(NGATE + wgo) * FSTR, (unsigned)o);

      // reduce 4 k-quarters and store out[:, o-1, slice]
#pragma unroll
      for (int p = 0; p < 4; ++p) {
        int idx = p * 256 + tid;
        int b = idx >> 4, ce = idx & 15;
        float s = ob;
#pragma unroll
        for (int q = 0; q < 4; ++q)
          s += smem[((q * 4 + (b >> 4)) * 16 + (b & 15)) * 17 + ce];
        dout[((size_t)(b << 8) + (o - 1)) * OD + wgo * 16 + ce] = s;
      }
    }
  }
}

extern "C" void kernel_launch(void* const* d_in, const int* in_sizes, int n_in,
                              void* d_out, int out_size, void* d_ws, size_t ws_size,
                              hipStream_t stream) {
  const float* latent = (const float*)d_in[0];
  // d_in[1] = seq_len (256, hardcoded)
  const float* fc_w = (const float*)d_in[2];
  const float* fc_b = (const float*)d_in[3];
  const float* w_ih = (const float*)d_in[4];
  const float* w_hh = (const float*)d_in[5];
  const float* b_ih = (const float*)d_in[6];
  const float* b_hh = (const float*)d_in[7];
  const float* out_w = (const float*)d_in[8];
  const float* out_b = (const float*)d_in[9];

  unsigned* flags = (unsigned*)d_ws;                              // 160 flags @128B stride
  unsigned short* hbuf = (unsigned short*)((char*)d_ws + 32768);  // 4 * 64*1024 bf16
  float* dout = (float*)d_out;

  zero_k<<<1, 256, 0, stream>>>(flags);
  fc_h0<<<256, 256, 0, stream>>>(latent, fc_w, fc_b, hbuf);
  lstm_persist<<<NGATE + NOUT, 256, 0, stream>>>(w_ih, w_hh, b_ih, b_hh,
                                                 out_w, out_b, flags, hbuf, dout);
}

// Round 8
// 2891.288 us; speedup vs baseline: 1.0102x; 1.0102x over previous
//
#include <hip/hip_runtime.h>
#include <hip/hip_bf16.h>

typedef __attribute__((ext_vector_type(8))) short bf16x8;
typedef __attribute__((ext_vector_type(4))) float f32x4;

#define NB 64
#define HD 1024
#define LD 256
#define OD 512
#define SQ 256
#define NGATE 128
#define NOUT 32
#define HN (NB * HD)
#define FSTR 32  // flag stride in u32 (128 B): one LLC line per flag, single writer

static __device__ __forceinline__ unsigned short f2bf(float f) {
  union { float f; unsigned u; } v; v.f = f;
  unsigned r = v.u + 0x7fffu + ((v.u >> 16) & 1u);
  return (unsigned short)(r >> 16);
}

static __device__ __forceinline__ bf16x8 cvt8(f32x4 x, f32x4 y) {
  bf16x8 r;
  r[0] = (short)f2bf(x[0]); r[1] = (short)f2bf(x[1]);
  r[2] = (short)f2bf(x[2]); r[3] = (short)f2bf(x[3]);
  r[4] = (short)f2bf(y[0]); r[5] = (short)f2bf(y[1]);
  r[6] = (short)f2bf(y[2]); r[7] = (short)f2bf(y[3]);
  return r;
}

static __device__ __forceinline__ bf16x8 ld_cvt(const float* p) {
  const f32x4* q = (const f32x4*)p;
  return cvt8(q[0], q[1]);
}
static __device__ __forceinline__ bf16x8 ld_cvt_sum(const float* p, const float* p2) {
  const f32x4* q = (const f32x4*)p;
  const f32x4* r = (const f32x4*)p2;
  return cvt8(q[0] + r[0], q[1] + r[1]);
}

static __device__ __forceinline__ float sigm(float x) { return 1.0f / (1.0f + __expf(-x)); }
static __device__ __forceinline__ float tanh_f(float x) {
  float t = __expf(-2.0f * fabsf(x));
  float r = (1.0f - t) / (1.0f + t);
  return copysignf(r, x);
}

static __device__ __forceinline__ unsigned ldflag(const unsigned* p) {
  return __hip_atomic_load(p, __ATOMIC_RELAXED, __HIP_MEMORY_SCOPE_AGENT);
}
static __device__ __forceinline__ void stflag(unsigned* p, unsigned v) {
  __hip_atomic_store(p, v, __ATOMIC_RELAXED, __HIP_MEMORY_SCOPE_AGENT);
}

// agent-coherent (LLC-direct, sc1) h reads
static __device__ __forceinline__ bf16x8 ld_h16(const unsigned short* p) {
  const unsigned long long* q = (const unsigned long long*)p;
  unsigned long long lo = __hip_atomic_load(q, __ATOMIC_RELAXED, __HIP_MEMORY_SCOPE_AGENT);
  unsigned long long hi = __hip_atomic_load(q + 1, __ATOMIC_RELAXED, __HIP_MEMORY_SCOPE_AGENT);
  union { unsigned long long v[2]; bf16x8 b; } u;
  u.v[0] = lo; u.v[1] = hi;
  return u.b;
}

// ---------------- h0 = latent @ fc_w^T + fc_b ---------------------------------
__global__ void fc_h0(const float* __restrict__ latent, const float* __restrict__ fcw,
                      const float* __restrict__ fcb, unsigned short* __restrict__ h0) {
  int gid = blockIdx.x * 256 + threadIdx.x;   // 65536 = 64*1024
  int b = gid >> 10, j = gid & 1023;
  const f32x4* lr = (const f32x4*)(latent + (size_t)b * LD);
  const f32x4* wr = (const f32x4*)(fcw + (size_t)j * LD);
  float s = fcb[j];
#pragma unroll 8
  for (int k = 0; k < LD / 4; ++k) {
    f32x4 a = lr[k], w = wr[k];
    s += a[0] * w[0] + a[1] * w[1] + a[2] * w[2] + a[3] * w[3];
  }
  h0[(size_t)b * HD + j] = f2bf(s);
}

// ---------------- zero flag region ---------------------------------------------
__global__ void zero_k(unsigned* __restrict__ flags) {
  for (int i = threadIdx.x; i < (NGATE + NOUT) * FSTR; i += 256) flags[i] = 0;
}

// ---------------- persistent LSTM kernel --------------------------------------
// blocks 0..127: gate WGs (8 hidden units each). blocks 128..159: out WGs (16 out rows).
// flags[i*FSTR]        (i<128): gate WG i completed steps count
// flags[(128+j)*FSTR]  (j<32) : out WG j has finished READING h_o (value o)
__global__ __launch_bounds__(256, 1)
void lstm_persist(const float* __restrict__ w_ih, const float* __restrict__ w_hh,
                  const float* __restrict__ b_ih, const float* __restrict__ b_hh,
                  const float* __restrict__ out_w, const float* __restrict__ out_b,
                  unsigned* __restrict__ flags, unsigned short* __restrict__ hbuf,
                  float* __restrict__ dout) {
  // combined bf16(w_ih+w_hh) weights, staged ONCE, in MFMA-fragment order:
  // [kh][w01][ks][col][kg][8] -> each lane's ds_read_b128 is 16B contiguous,
  // wave-wide 1024B linear (conflict-free). 64 KiB. LDS residency is
  // deterministic -- the register allocator cannot rematerialize these.
  __shared__ unsigned short wlds[2][2][16][16][4][8];
  __shared__ float smem[4352];
  const int tid = threadIdx.x;
  const int lane = tid & 63;
  const int wid = tid >> 6;
  const int col = lane & 15;   // MFMA n/row-within-tile index
  const int kg = lane >> 4;    // MFMA k-group

  if (blockIdx.x < NGATE) {
    // =================== GATE WG ===================
    const int wg = blockIdx.x;
    const int mh = wid & 1;   // batch half (32)
    const int kh = wid >> 1;  // k half (512)
    const int u = col & 7;
    const int grow0 = ((col >> 3) + 0) * HD + wg * 8 + u;  // rows: i|f
    const int grow1 = ((col >> 3) + 2) * HD + wg * 8 + u;  // rows: g|o
    const int kb = kh * 512 + kg * 8;

    const float bias0 = b_ih[grow0] + b_hh[grow0];
    const float bias1 = b_ih[grow1] + b_hh[grow1];

    // one-time stage of combined weights into LDS (mh==0 waves only)
    if (mh == 0) {
#pragma unroll
      for (int ks = 0; ks < 16; ++ks) {
        bf16x8 w0 = ld_cvt_sum(w_ih + (size_t)grow0 * HD + kb + ks * 32,
                               w_hh + (size_t)grow0 * HD + kb + ks * 32);
        bf16x8 w1 = ld_cvt_sum(w_ih + (size_t)grow1 * HD + kb + ks * 32,
                               w_hh + (size_t)grow1 * HD + kb + ks * 32);
        *(bf16x8*)&wlds[kh][0][ks][col][kg][0] = w0;
        *(bf16x8*)&wlds[kh][1][ks][col][kg][0] = w1;
      }
    }

    float c[2][4];
#pragma unroll
    for (int mt = 0; mt < 2; ++mt)
#pragma unroll
      for (int r = 0; r < 4; ++r) c[mt][r] = 0.0f;

    // wave0 poll pointers: lane covers gate flags {lane, lane+64}, out flag lane&31
    const unsigned* gp0 = flags + (size_t)lane * FSTR;
    const unsigned* gp1 = flags + (size_t)(lane + 64) * FSTR;
    const unsigned* op = flags + (size_t)(NGATE + (lane & 31)) * FSTR;

    for (int g = 0; g < SQ; ++g) {
      if (wid == 0 && g >= 1) {
        unsigned gtgt = (unsigned)g;                       // all gates done step g-1
        unsigned otgt = (g >= 4) ? (unsigned)(g - 3) : 0u; // out WGs done reading h_{g-3}
        for (;;) {
          unsigned m = min(ldflag(gp0), ldflag(gp1));
          unsigned om = (lane < 32) ? ldflag(op) : 0xffffffffu;
          if (__all((int)(m >= gtgt && om >= otgt))) break;
          __builtin_amdgcn_s_sleep(1);
        }
      }
      __syncthreads();   // also covers the one-time wlds staging at g==0
      asm volatile("" ::: "memory");

      const unsigned short* hb = hbuf + (size_t)(g & 3) * HN;
      const unsigned short* a0b = hb + (size_t)(mh * 32 + col) * HD + kb;
      const unsigned short* a1b = hb + (size_t)(mh * 32 + 16 + col) * HD + kb;

      // Preload ALL A-fragments first (atomics issue back-to-back, one LLC RTT).
      bf16x8 A0[16], A1[16];
#pragma unroll
      for (int ks = 0; ks < 16; ++ks) {
        A0[ks] = ld_h16(a0b + ks * 32);
        A1[ks] = ld_h16(a1b + ks * 32);
      }

      f32x4 acc[2][2];
#pragma unroll
      for (int mt = 0; mt < 2; ++mt)
#pragma unroll
        for (int nt = 0; nt < 2; ++nt) acc[mt][nt] = (f32x4){0.f, 0.f, 0.f, 0.f};

      if (g == 0) {  // x0 = 0: gates = h0 @ w_hh^T (stream B-frags from global)
#pragma unroll
        for (int ks = 0; ks < 16; ++ks) {
          bf16x8 w0 = ld_cvt(w_hh + (size_t)grow0 * HD + kb + ks * 32);
          bf16x8 w1 = ld_cvt(w_hh + (size_t)grow1 * HD + kb + ks * 32);
          acc[0][0] = __builtin_amdgcn_mfma_f32_16x16x32_bf16(A0[ks], w0, acc[0][0], 0, 0, 0);
          acc[0][1] = __builtin_amdgcn_mfma_f32_16x16x32_bf16(A0[ks], w1, acc[0][1], 0, 0, 0);
          acc[1][0] = __builtin_amdgcn_mfma_f32_16x16x32_bf16(A1[ks], w0, acc[1][0], 0, 0, 0);
          acc[1][1] = __builtin_amdgcn_mfma_f32_16x16x32_bf16(A1[ks], w1, acc[1][1], 0, 0, 0);
        }
      } else {       // B-frags from LDS (ds_read_b128, conflict-free)
#pragma unroll
        for (int ks = 0; ks < 16; ++ks) {
          bf16x8 w0 = *(const bf16x8*)&wlds[kh][0][ks][col][kg][0];
          bf16x8 w1 = *(const bf16x8*)&wlds[kh][1][ks][col][kg][0];
          acc[0][0] = __builtin_amdgcn_mfma_f32_16x16x32_bf16(A0[ks], w0, acc[0][0], 0, 0, 0);
          acc[0][1] = __builtin_amdgcn_mfma_f32_16x16x32_bf16(A0[ks], w1, acc[0][1], 0, 0, 0);
          acc[1][0] = __builtin_amdgcn_mfma_f32_16x16x32_bf16(A1[ks], w0, acc[1][0], 0, 0, 0);
          acc[1][1] = __builtin_amdgcn_mfma_f32_16x16x32_bf16(A1[ks], w1, acc[1][1], 0, 0, 0);
        }
      }

      // K-reduction across kh via LDS
      if (kh == 1) {
#pragma unroll
        for (int mt = 0; mt < 2; ++mt)
#pragma unroll
          for (int nt = 0; nt < 2; ++nt)
#pragma unroll
            for (int r = 0; r < 4; ++r)
              smem[(((mh * 2 + mt) * 2 + nt) * 16 + kg * 4 + r) * 17 + col] = acc[mt][nt][r];
      }
      __syncthreads();
      if (kh == 0) {
        unsigned short* hn = hbuf + (size_t)((g + 1) & 3) * HN;
#pragma unroll
        for (int mt = 0; mt < 2; ++mt) {
#pragma unroll
          for (int r = 0; r < 4; ++r) {
            float gi = acc[mt][0][r] +
                       smem[(((mh * 2 + mt) * 2 + 0) * 16 + kg * 4 + r) * 17 + col] + bias0;
            float gg = acc[mt][1][r] +
                       smem[(((mh * 2 + mt) * 2 + 1) * 16 + kg * 4 + r) * 17 + col] + bias1;
            float gi_p = __shfl_xor(gi, 8);
            float gg_p = __shfl_xor(gg, 8);
            float I = (col < 8) ? gi : gi_p;
            float F = (col < 8) ? gi_p : gi;
            float G = (col < 8) ? gg : gg_p;
            float Oo = (col < 8) ? gg_p : gg;
            float cn = sigm(F) * c[mt][r] + sigm(I) * tanh_f(G);
            c[mt][r] = cn;
            float hv = sigm(Oo) * tanh_f(cn);
            // publish h via packed u32 atomic swap: commits AT the LLC (no posted-
            // store window vs the flag).
            unsigned hb16 = (unsigned)f2bf(hv);
            unsigned pv = (unsigned)__shfl_xor((int)hb16, 1);
            if (col < 8 && (col & 1) == 0) {
              unsigned val = (hb16 & 0xffffu) | (pv << 16);
              unsigned* p = (unsigned*)(hn +
                  (size_t)(mh * 32 + mt * 16 + kg * 4 + r) * HD + wg * 8 + col);
              __hip_atomic_exchange(p, val, __ATOMIC_RELAXED, __HIP_MEMORY_SCOPE_AGENT);
            }
          }
        }
      }
      __syncthreads();  // each wave drains vmcnt (swaps committed at LLC) before flag
      if (tid == 0) stflag(flags + (size_t)wg * FSTR, (unsigned)(g + 1));
    }
  } else {
    // =================== OUT WG ===================
    const int wgo = blockIdx.x - NGATE;
    const int kq = wid;  // k quarter (256)
    const int orow = wgo * 16 + col;
    bf16x8 Bo[8];
#pragma unroll
    for (int ks = 0; ks < 8; ++ks)
      Bo[ks] = ld_cvt(out_w + (size_t)orow * HD + kq * 256 + ks * 32 + kg * 8);
    const float ob = out_b[wgo * 16 + (tid & 15)];

    const unsigned* gp0 = flags + (size_t)lane * FSTR;
    const unsigned* gp1 = flags + (size_t)(lane + 64) * FSTR;

    for (int o = 1; o <= SQ; ++o) {
      if (wid == 0) {
        unsigned tg = (unsigned)o;  // h_o ready
        for (;;) {
          unsigned m = min(ldflag(gp0), ldflag(gp1));
          if (__all((int)(m >= tg))) break;
          __builtin_amdgcn_s_sleep(1);
        }
      }
      __syncthreads();
      asm volatile("" ::: "memory");

      const unsigned short* hb = hbuf + (size_t)(o & 3) * HN;

      // Preload all 32 A-fragments (source order) for one pipelined LLC burst.
      bf16x8 A[8][4];
#pragma unroll
      for (int ks = 0; ks < 8; ++ks)
#pragma unroll
        for (int mt = 0; mt < 4; ++mt)
          A[ks][mt] = ld_h16(hb + (size_t)(mt * 16 + col) * HD + kq * 256 + ks * 32 + kg * 8);

      f32x4 oacc[4];
#pragma unroll
      for (int mt = 0; mt < 4; ++mt) oacc[mt] = (f32x4){0.f, 0.f, 0.f, 0.f};
#pragma unroll
      for (int ks = 0; ks < 8; ++ks)
#pragma unroll
        for (int mt = 0; mt < 4; ++mt)
          oacc[mt] = __builtin_amdgcn_mfma_f32_16x16x32_bf16(A[ks][mt], Bo[ks], oacc[mt], 0, 0, 0);

      // partials to LDS
#pragma unroll
      for (int mt = 0; mt < 4; ++mt)
#pragma unroll
        for (int r = 0; r < 4; ++r)
          smem[((kq * 4 + mt) * 16 + kg * 4 + r) * 17 + col] = oacc[mt][r];
      __syncthreads();  // drains h loads (vmcnt) + orders LDS
      if (tid == 0) stflag(flags + (size_t)(NGATE + wgo) * FSTR, (unsigned)o);

      // reduce 4 k-quarters and store out[:, o-1, slice]
#pragma unroll
      for (int p = 0; p < 4; ++p) {
        int idx = p * 256 + tid;
        int b = idx >> 4, ce = idx & 15;
        float s = ob;
#pragma unroll
        for (int q = 0; q < 4; ++q)
          s += smem[((q * 4 + (b >> 4)) * 16 + (b & 15)) * 17 + ce];
        dout[((size_t)(b << 8) + (o - 1)) * OD + wgo * 16 + ce] = s;
      }
    }
  }
}

extern "C" void kernel_launch(void* const* d_in, const int* in_sizes, int n_in,
                              void* d_out, int out_size, void* d_ws, size_t ws_size,
                              hipStream_t stream) {
  const float* latent = (const float*)d_in[0];
  // d_in[1] = seq_len (256, hardcoded)
  const float* fc_w = (const float*)d_in[2];
  const float* fc_b = (const float*)d_in[3];
  const float* w_ih = (const float*)d_in[4];
  const float* w_hh = (const float*)d_in[5];
  const float* b_ih = (const float*)d_in[6];
  const float* b_hh = (const float*)d_in[7];
  const float* out_w = (const float*)d_in[8];
  const float* out_b = (const float*)d_in[9];

  unsigned* flags = (unsigned*)d_ws;                              // 160 flags @128B stride
  unsigned short* hbuf = (unsigned short*)((char*)d_ws + 32768);  // 4 * 64*1024 bf16
  float* dout = (float*)d_out;

  zero_k<<<1, 256, 0, stream>>>(flags);
  fc_h0<<<256, 256, 0, stream>>>(latent, fc_w, fc_b, hbuf);
  lstm_persist<<<NGATE + NOUT, 256, 0, stream>>>(w_ih, w_hh, b_ih, b_hh,
                                                 out_w, out_b, flags, hbuf, dout);
}